// Round 14
// baseline (562.102 us; speedup 1.0000x reference)
//
#include <hip/hip_runtime.h>

#define N_NODES   10000
#define N_EDGES   50000
#define N_GRAPHS  64
#define NODE_DIM  32
#define EDGE_DIM  16
#define HID       64
#define EHID      128
#define T_STEPS   3
#define S2S_STEPS 6
#define TMB       5     // tm tiles per block (BT register-amortization)

typedef _Float16 half_t;
typedef _Float16 f16x8 __attribute__((ext_vector_type(8)));
typedef float    f32x4 __attribute__((ext_vector_type(4)));

__device__ __forceinline__ float sigf(float x){ return 1.0f/(1.0f + expf(-x)); }

__global__ void k_zero(float* p, int n){
  int i = blockIdx.x*256 + threadIdx.x;
  if (i < n) p[i] = 0.0f;
}

// h = nf @ W_proj + b_proj   (N x 64)
// [SESSION NOTES — measured, do not retry:
//  - merged prep-style kernels (r10 k_gru_prep, r11 k_proj_prep): ~75-97us
//    near-idle stall windows; separate kernels measured-fast.
//  - r10 register Hid16-gather prefetch in fused kernel: 62->93us.
//  - r12 LDS double-buffered edge prefetch: 62->65us (neutral-negative).
//  - r7/r8 atomic-free Msg detour: net worse than atomics (606/622 vs 581).
//  - r1 coalesced-WcT s2s gates: 56->95us.]
__global__ void k_proj(const float* __restrict__ nf, const float* __restrict__ Wp,
                       const float* __restrict__ bp, float* __restrict__ h){
  int idx = blockIdx.x*256 + threadIdx.x;
  if (idx >= N_NODES*HID) return;
  int n = idx >> 6;
  int c = idx & 63;
  float acc = bp[c];
  const float* row = nf + (size_t)n*NODE_DIM;
  for (int j = 0; j < NODE_DIM; ++j)
    acc = fmaf(row[j], Wp[j*HID + c], acc);
  h[idx] = acc;
}

// Mm (fp32, fallback path)
__global__ void k_tw2(const float* __restrict__ W2, float* __restrict__ Mm){
  int idx = blockIdx.x*256 + threadIdx.x;
  if (idx >= 64*8192) return;
  int j = idx >> 13; int o = idx & 8191; int k = o >> 6; int i = o & 63;
  Mm[idx] = W2[(size_t)k*4096 + i*64 + j];
}

// BT: W2 in MFMA B-fragment order (fp16), built once.
__global__ void k_w2bt(const float* __restrict__ W2, half_t* __restrict__ BT){
  int idx = blockIdx.x*256 + threadIdx.x;
  if (idx >= 512*2*64*8) return;
  int j    = idx & 7;
  int lane = (idx >> 3) & 63;
  int tk   = (idx >> 9) & 1;
  int tn   = idx >> 10;
  int k = tk*32 + ((lane >> 4) << 3) + j;
  int o = tn*16 + (lane & 15);
  BT[idx] = (half_t)W2[(size_t)(o >> 6)*4096 + (o & 63)*64 + k];
}

// Per-step prep (r14: AT transform removed — fused kernel now reads A-frags
// directly from h, which is L2-resident; kills 1.28MB AT write + 10MB read).
__global__ void k_prep(const float* __restrict__ h, const float* __restrict__ be2,
                       float* __restrict__ m, float* __restrict__ bhp){
  int idx = blockIdx.x*256 + threadIdx.x;
  if (idx >= N_NODES*HID) return;
  m[idx] = 0.0f;
  int n = idx >> 6, i = idx & 63;
  float acc = 0.0f;
  const float* row = be2 + (size_t)i*64;
  const float* hr  = h + (size_t)n*64;
  for (int j = 0; j < 64; ++j)
    acc = fmaf(row[j], hr[j], acc);
  bhp[idx] = acc;
}

// GRU weight transposes
__global__ void k_twg(const float* __restrict__ Wg, const float* __restrict__ Wh,
                      float* __restrict__ WgT, float* __restrict__ WhT){
  int idx = blockIdx.x*256 + threadIdx.x;
  if (idx >= 192*64) return;
  int row = idx >> 6;
  int j   = idx & 63;
  WgT[j*192 + row] = Wg[(size_t)row*64 + j];
  WhT[j*192 + row] = Wh[(size_t)row*64 + j];
}

// Hid = relu(ef @ W_e1 + b_e1)  fp32 (fallback path)
__global__ void k_ehid(const float* __restrict__ ef, const float* __restrict__ W1,
                       const float* __restrict__ b1, float* __restrict__ Hid){
  int idx = blockIdx.x*256 + threadIdx.x;
  if (idx >= N_EDGES*EHID) return;
  int e = idx >> 7, c = idx & 127;
  float acc = b1[c];
  const float* er = ef + (size_t)e*EDGE_DIM;
  for (int j = 0; j < EDGE_DIM; ++j)
    acc = fmaf(er[j], W1[j*EHID + c], acc);
  Hid[idx] = fmaxf(acc, 0.0f);
}

// Hid16 = relu(ef @ W_e1 + b_e1) in fp16 (MFMA message path)
__global__ void k_ehid16(const float* __restrict__ ef, const float* __restrict__ W1,
                         const float* __restrict__ b1, half_t* __restrict__ Hid16){
  int idx = blockIdx.x*256 + threadIdx.x;
  if (idx >= N_EDGES*EHID) return;
  int e = idx >> 7, c = idx & 127;
  float acc = b1[c];
  const float* er = ef + (size_t)e*EDGE_DIM;
  for (int j = 0; j < EDGE_DIM; ++j)
    acc = fmaf(er[j], W1[j*EHID + c], acc);
  Hid16[idx] = (half_t)fmaxf(acc, 0.0f);
}

// bh[n,i] = sum_j be2[i*64+j] * h[n,j]  (fallback path)
__global__ void k_bh(const float* __restrict__ h, const float* __restrict__ be2,
                     float* __restrict__ bh){
  int idx = blockIdx.x*256 + threadIdx.x;
  if (idx >= N_NODES*HID) return;
  int n = idx >> 6, i = idx & 63;
  float acc = 0.0f;
  const float* row = be2 + (size_t)i*64;
  const float* hr  = h + (size_t)n*64;
  for (int j = 0; j < 64; ++j)
    acc = fmaf(row[j], hr[j], acc);
  bh[idx] = acc;
}

// ---- CSR builders ----
__global__ void k_hist(const int* __restrict__ ids, int* __restrict__ deg){
  int e = blockIdx.x*256 + threadIdx.x;
  if (e >= N_EDGES) return;
  atomicAdd(&deg[ids[e]], 1);
}

__global__ void k_scan(const int* __restrict__ deg, int* __restrict__ rowptr,
                       int* __restrict__ cursor){
  __shared__ int part[256];
  int t = threadIdx.x;
  int base = t*40;
  int s = 0;
  for (int i = 0; i < 40; ++i){
    int idx = base + i;
    if (idx < N_NODES) s += deg[idx];
  }
  part[t] = s;
  __syncthreads();
  for (int off = 1; off < 256; off <<= 1){
    int v = (t >= off) ? part[t - off] : 0;
    __syncthreads();
    part[t] += v;
    __syncthreads();
  }
  int run = (t > 0) ? part[t - 1] : 0;
  for (int i = 0; i < 40; ++i){
    int idx = base + i;
    if (idx < N_NODES){
      rowptr[idx] = run;
      cursor[idx] = run;
      run += deg[idx];
    }
  }
  if (t == 255) rowptr[N_NODES] = run;
}

__global__ void k_scatter(const int* __restrict__ ids, int* __restrict__ cursor,
                          int* __restrict__ csr){
  int e = blockIdx.x*256 + threadIdx.x;
  if (e >= N_EDGES) return;
  int v = ids[e];
  int pos = atomicAdd(&cursor[v], 1);
  csr[pos] = e;
}

// ---- FUSED cgemm + message kernel (mfma path), r14 ----
// = r9 kernel (62.4us measured) with A-fragments loaded DIRECTLY from h
// (4x float4 + inline cvt; same values as the old AT fp16 buffer, which is
// now eliminated). Address is index-computed (not data-dependent), so the
// dependency structure is unchanged vs r9 — unlike r10's failed gather
// prefetch. BT register-resident across TMB=5 tiles; atomic scatter.
__global__ __launch_bounds__(256, 2)
void MPNN_55705725829535_kernel(const float* __restrict__ h,
                                const half_t* __restrict__ BT,
                                const int* __restrict__ rowptr,
                                const int* __restrict__ csr,
                                const int* __restrict__ ei,
                                const half_t* __restrict__ Hid16,
                                const float* __restrict__ bh,
                                float* __restrict__ m){
  __shared__ half_t Ct[16][2][520];
  __shared__ int edgW[4][4][16];
  __shared__ int dstW[4][4][16];
  int wv   = threadIdx.x >> 6;
  int lane = threadIdx.x & 63;
  int quad = lane >> 4;
  int colb = lane & 15;
  int tmg = blockIdx.x;          // 0..124 (group of TMB tm tiles)
  int q   = blockIdx.y;          // 0..3   (i-quarter)
  int kh  = blockIdx.z;          // 0..1   (k-half)

  // ---- load this block's BT slice into registers (once) ----
  f16x8 B0r[2][8], B1r[2][8];
  #pragma unroll
  for (int ktl = 0; ktl < 2; ++ktl)
    #pragma unroll
    for (int jj = 0; jj < 8; ++jj){
      int ke = (kh*2 + ktl)*32 + wv*8 + jj;
      const f16x8* Bb = (const f16x8*)BT + (size_t)(ke*4 + q)*128;
      B0r[ktl][jj] = Bb[lane];
      B1r[ktl][jj] = Bb[64 + lane];
    }

  for (int tt = 0; tt < TMB; ++tt){
    int tm = tmg*TMB + tt;
    // ---- A-fragments straight from h (fp32->fp16 inline; h is L2-resident)
    // a0: k = quad*8 + j (tk=0), a1: k = 32 + quad*8 + j (tk=1),
    // row = tm*16 + colb  — identical values to the old AT buffer.
    const float* hrow = h + (size_t)(tm*16 + colb)*64 + quad*8;
    float4 v0 = *(const float4*)(hrow);
    float4 v1 = *(const float4*)(hrow + 4);
    float4 w0 = *(const float4*)(hrow + 32);
    float4 w1 = *(const float4*)(hrow + 36);
    f16x8 a0, a1;
    a0[0]=(half_t)v0.x; a0[1]=(half_t)v0.y; a0[2]=(half_t)v0.z; a0[3]=(half_t)v0.w;
    a0[4]=(half_t)v1.x; a0[5]=(half_t)v1.y; a0[6]=(half_t)v1.z; a0[7]=(half_t)v1.w;
    a1[0]=(half_t)w0.x; a1[1]=(half_t)w0.y; a1[2]=(half_t)w0.z; a1[3]=(half_t)w0.w;
    a1[4]=(half_t)w1.x; a1[5]=(half_t)w1.y; a1[6]=(half_t)w1.z; a1[7]=(half_t)w1.w;

    // ---- cooperative prefetch of edge ids + dst ids for this wave's 4 nodes
    {
      int nodeL = wv*4 + quad;          // lane-quad -> node c
      int sL = tm*16 + nodeL;
      int begL = rowptr[sL];
      int endL = rowptr[sL + 1];
      int eL = (colb < endL - begL) ? csr[begL + colb] : -1;
      edgW[wv][quad][colb] = eL;
      dstW[wv][quad][colb] = (eL >= 0) ? ei[eL] : -1;
    }

    // ---- phase 1: C-slice GEMM into LDS (register B-frags, 32 MFMA) ----
    #pragma unroll
    for (int ktl = 0; ktl < 2; ++ktl){
      f32x4 acc[8];
      #pragma unroll
      for (int jj = 0; jj < 8; ++jj){
        acc[jj][0]=0.f; acc[jj][1]=0.f; acc[jj][2]=0.f; acc[jj][3]=0.f;
      }
      #pragma unroll
      for (int jj = 0; jj < 8; ++jj){
        acc[jj] = __builtin_amdgcn_mfma_f32_16x16x32_f16(a0, B0r[ktl][jj], acc[jj], 0, 0, 0);
        acc[jj] = __builtin_amdgcn_mfma_f32_16x16x32_f16(a1, B1r[ktl][jj], acc[jj], 0, 0, 0);
      }
      #pragma unroll
      for (int r = 0; r < 4; ++r){
        int node = quad*4 + r;       // 0..15
        f16x8 v;
        #pragma unroll
        for (int jj = 0; jj < 8; ++jj) v[jj] = (half_t)acc[jj][r];
        *(f16x8*)&Ct[node][ktl][(wv*16 + colb)*8] = v;
      }
    }
    __syncthreads();

    // ---- phase 2: per-node message MFMAs (k-half), atomic scatter ----
    for (int c = 0; c < 4; ++c){
      int node = wv*4 + c;           // 0..15
      int s = tm*16 + node;
      int beg  = rowptr[s];
      int endp = rowptr[s + 1];
      if (beg == endp) continue;
      f16x8 B0 = *(const f16x8*)&Ct[node][0][lane*8];
      f16x8 B1 = *(const f16x8*)&Ct[node][1][lane*8];
      float bhc = (kh == 0) ? bh[(size_t)s*64 + q*16 + colb] : 0.0f;
      // group 0: prefetched edge/dst lists
      int gn0 = endp - beg; if (gn0 > 16) gn0 = 16;
      {
        f16x8 A0, A1;
        int e = (colb < gn0) ? edgW[wv][c][colb] : -1;
        if (e >= 0){
          const f16x8* Hb = (const f16x8*)(Hid16 + (size_t)e*128) + quad;
          A0 = Hb[(kh*2 + 0)*4];
          A1 = Hb[(kh*2 + 1)*4];
        } else {
          #pragma unroll
          for (int p = 0; p < 8; ++p){ A0[p] = (half_t)0; A1[p] = (half_t)0; }
        }
        f32x4 acc;
        acc[0]=0.f; acc[1]=0.f; acc[2]=0.f; acc[3]=0.f;
        acc = __builtin_amdgcn_mfma_f32_16x16x32_f16(A0, B0, acc, 0, 0, 0);
        acc = __builtin_amdgcn_mfma_f32_16x16x32_f16(A1, B1, acc, 0, 0, 0);
        #pragma unroll
        for (int r = 0; r < 4; ++r){
          int jrow = quad*4 + r;
          if (jrow < gn0){
            int d = dstW[wv][c][jrow];
            atomicAdd(&m[(size_t)d*64 + q*16 + colb], acc[r] + bhc);
          }
        }
      }
      // remaining groups (deg > 16; rare)
      for (int gbeg = beg + 16; gbeg < endp; gbeg += 16){
        int gn = endp - gbeg; if (gn > 16) gn = 16;
        if (lane < 16){
          int e2 = (lane < gn) ? csr[gbeg + lane] : -1;
          edgW[wv][c][lane] = e2;
          dstW[wv][c][lane] = (e2 >= 0) ? ei[e2] : -1;
        }
        f16x8 A0, A1;
        int e = (colb < gn) ? edgW[wv][c][colb] : -1;
        if (e >= 0){
          const f16x8* Hb = (const f16x8*)(Hid16 + (size_t)e*128) + quad;
          A0 = Hb[(kh*2 + 0)*4];
          A1 = Hb[(kh*2 + 1)*4];
        } else {
          #pragma unroll
          for (int p = 0; p < 8; ++p){ A0[p] = (half_t)0; A1[p] = (half_t)0; }
        }
        f32x4 acc;
        acc[0]=0.f; acc[1]=0.f; acc[2]=0.f; acc[3]=0.f;
        acc = __builtin_amdgcn_mfma_f32_16x16x32_f16(A0, B0, acc, 0, 0, 0);
        acc = __builtin_amdgcn_mfma_f32_16x16x32_f16(A1, B1, acc, 0, 0, 0);
        #pragma unroll
        for (int r = 0; r < 4; ++r){
          int jrow = quad*4 + r;
          if (jrow < gn){
            int d = dstW[wv][c][jrow];
            atomicAdd(&m[(size_t)d*64 + q*16 + colb], acc[r] + bhc);
          }
        }
      }
    }
    __syncthreads();
  }
}

// scalar cgemm (fallback, chunked)
__global__ void k_cgemm(const float* __restrict__ h, const float* __restrict__ Mm,
                        half_t* __restrict__ C, int lo, int hi){
  __shared__ float hs[16][64];
  int n0 = lo + blockIdx.x*16;
  int o0 = blockIdx.y*256 + threadIdx.x;
  for (int idx = threadIdx.x; idx < 16*64; idx += 256){
    int nn = idx >> 6, j = idx & 63;
    int node = n0 + nn;
    hs[nn][j] = (node < hi) ? h[(size_t)node*64 + j] : 0.0f;
  }
  __syncthreads();
  float acc0[16], acc1[16];
  #pragma unroll
  for (int nn = 0; nn < 16; ++nn){ acc0[nn] = 0.0f; acc1[nn] = 0.0f; }
  for (int j4 = 0; j4 < 16; ++j4){
    const float* M0 = Mm + (size_t)(j4*4)*8192;
    float a0 = M0[o0],            b0 = M0[o0 + 4096];
    float a1 = M0[8192 + o0],     b1 = M0[8192 + o0 + 4096];
    float a2 = M0[2*8192 + o0],   b2 = M0[2*8192 + o0 + 4096];
    float a3 = M0[3*8192 + o0],   b3 = M0[3*8192 + o0 + 4096];
    #pragma unroll
    for (int nn = 0; nn < 16; ++nn){
      float4 hv = *(const float4*)&hs[nn][j4*4];
      acc0[nn] = fmaf(hv.x, a0, acc0[nn]);
      acc1[nn] = fmaf(hv.x, b0, acc1[nn]);
      acc0[nn] = fmaf(hv.y, a1, acc0[nn]);
      acc1[nn] = fmaf(hv.y, b1, acc1[nn]);
      acc0[nn] = fmaf(hv.z, a2, acc0[nn]);
      acc1[nn] = fmaf(hv.z, b2, acc1[nn]);
      acc0[nn] = fmaf(hv.w, a3, acc0[nn]);
      acc1[nn] = fmaf(hv.w, b3, acc1[nn]);
    }
  }
  #pragma unroll
  for (int nn = 0; nn < 16; ++nn){
    int node = n0 + nn;
    if (node < hi){
      half_t* Cr = C + (size_t)(node - lo)*8192;
      Cr[o0]        = (half_t)acc0[nn];
      Cr[o0 + 4096] = (half_t)acc1[nn];
    }
  }
}

// old-style streaming msg kernel (fallback path)
__global__ void k_msg_csr(const int* __restrict__ rowptr,
                          const int* __restrict__ csr,
                          const int* __restrict__ ei,
                          const float* __restrict__ Hid,
                          const half_t* __restrict__ C,
                          const float* __restrict__ bh,
                          float* __restrict__ m, int lo, int hi){
  __shared__ float hidL[4][8][128];
  int wave = threadIdx.x >> 6;
  int lane = threadIdx.x & 63;
  int s = lo + blockIdx.x*4 + wave;
  if (s >= hi) return;
  int beg = rowptr[s];
  int endp = rowptr[s + 1];
  if (beg == endp) return;
  float bhv = bh[(size_t)s*64 + lane];
  const half_t* Cb = C + (size_t)(s - lo)*8192 + lane;
  float (*hl)[128] = hidL[wave];
  for (int gbeg = beg; gbeg < endp; gbeg += 8){
    int gn = endp - gbeg; if (gn > 8) gn = 8;
    int dsts[8];
    int e0 = csr[gbeg];
    #pragma unroll
    for (int j = 0; j < 8; ++j){
      int e = (j < gn) ? csr[gbeg + j] : e0;
      dsts[j] = ei[e];
      hl[j][lane]      = Hid[(size_t)e*128 + lane];
      hl[j][lane + 64] = Hid[(size_t)e*128 + 64 + lane];
    }
    float acc[8];
    #pragma unroll
    for (int j = 0; j < 8; ++j) acc[j] = 0.0f;
    #pragma unroll 4
    for (int k = 0; k < 128; ++k){
      float c = (float)Cb[k*64];
      #pragma unroll
      for (int j = 0; j < 8; ++j)
        acc[j] = fmaf(hl[j][k], c, acc[j]);
    }
    for (int j = 0; j < gn; ++j)
      atomicAdd(&m[(size_t)dsts[j]*64 + lane], acc[j] + bhv);
  }
}

// fallback per-edge bilinear
__global__ void k_msg_fb(const int* __restrict__ ei, const float* __restrict__ ef,
                         const float* __restrict__ W1, const float* __restrict__ b1,
                         const float* __restrict__ W2, const float* __restrict__ be2,
                         const float* __restrict__ h, float* __restrict__ m){
  __shared__ float HidL[EHID];
  __shared__ __align__(16) float hsL[HID];
  int e = blockIdx.x;
  int t = threadIdx.x;
  int src = ei[N_EDGES + e];
  int dst = ei[e];
  {
    float a0 = b1[t];
    float a1 = b1[t + 64];
    const float* er = ef + (size_t)e*EDGE_DIM;
    for (int j = 0; j < EDGE_DIM; ++j){
      float ev = er[j];
      a0 = fmaf(ev, W1[j*EHID + t],      a0);
      a1 = fmaf(ev, W1[j*EHID + t + 64], a1);
    }
    HidL[t]      = fmaxf(a0, 0.0f);
    HidL[t + 64] = fmaxf(a1, 0.0f);
    hsL[t] = h[(size_t)src*64 + t];
  }
  __syncthreads();
  float acc = 0.0f;
  for (int k = 0; k < EHID; ++k){
    float s = HidL[k];
    if (s != 0.0f){
      const float* w = W2 + (size_t)k*4096 + t*64;
      float partial = 0.0f;
      for (int j = 0; j < 64; ++j)
        partial = fmaf(hsL[j], w[j], partial);
      acc = fmaf(s, partial, acc);
    }
  }
  {
    const float* w = be2 + (size_t)t*64;
    for (int j = 0; j < 64; ++j)
      acc = fmaf(hsL[j], w[j], acc);
  }
  atomicAdd(&m[(size_t)dst*64 + t], acc);
}

// GRU: 256 threads = 4 waves, 16 nodes/block (4 per wave).
__global__ void k_gru(float* __restrict__ h, const float* __restrict__ m,
                      const float* __restrict__ WgT, const float* __restrict__ WhT,
                      const float* __restrict__ bg, const float* __restrict__ bhb){
  __shared__ float mld[16][64];
  __shared__ float hld[16][64];
  int t  = threadIdx.x;
  int i  = t & 63;
  int wv = t >> 6;                  // 0..3
  int n0 = blockIdx.x*16;           // 625*16 == 10000 exactly
  for (int idx = t; idx < 16*64; idx += 256){
    int nn = idx >> 6, j = idx & 63;
    int node = n0 + nn;
    mld[nn][j] = m[(size_t)node*64 + j];
    hld[nn][j] = h[(size_t)node*64 + j];
  }
  __syncthreads();
  float xr[4], xz[4], xn[4], hr[4], hz[4], hn[4];
  #pragma unroll
  for (int c = 0; c < 4; ++c){
    xr[c] = bg[i];  xz[c] = bg[64 + i];  xn[c] = bg[128 + i];
    hr[c] = bhb[i]; hz[c] = bhb[64 + i]; hn[c] = bhb[128 + i];
  }
  for (int j = 0; j < 64; ++j){
    const float* wg = WgT + j*192;
    const float* wh = WhT + j*192;
    float wgr = wg[i], wgz = wg[64 + i], wgn = wg[128 + i];
    float whr = wh[i], whz = wh[64 + i], whn = wh[128 + i];
    #pragma unroll
    for (int c = 0; c < 4; ++c){
      int nn = wv*4 + c;
      float mj = mld[nn][j];
      float hj = hld[nn][j];
      xr[c] = fmaf(mj, wgr, xr[c]);
      xz[c] = fmaf(mj, wgz, xz[c]);
      xn[c] = fmaf(mj, wgn, xn[c]);
      hr[c] = fmaf(hj, whr, hr[c]);
      hz[c] = fmaf(hj, whz, hz[c]);
      hn[c] = fmaf(hj, whn, hn[c]);
    }
  }
  #pragma unroll
  for (int c = 0; c < 4; ++c){
    int nn = wv*4 + c;
    float r  = sigf(xr[c] + hr[c]);
    float z  = sigf(xz[c] + hz[c]);
    float nv = tanhf(xn[c] + r*hn[c]);
    h[(size_t)(n0 + nn)*64 + i] = (1.0f - z)*nv + z*hld[nn][i];
  }
}

// Set2Set + LSTM + readout; 512 threads (proven kernel — do not touch).
__global__ void k_s2s(const float* __restrict__ h,
                      const float* __restrict__ Wli, const float* __restrict__ Wlh,
                      const float* __restrict__ bli, const float* __restrict__ blh,
                      const float* __restrict__ Wm1, const float* __restrict__ bm1,
                      const float* __restrict__ Wm2, const float* __restrict__ bm2,
                      float* __restrict__ out){
  __shared__ float hc[157*65];
  __shared__ float ea[160];
  __shared__ float x[192];
  __shared__ float gpart[512];
  __shared__ float rsp[8][64];
  __shared__ float wredA[8];
  __shared__ float wredB[8];
  __shared__ float hsb[64];
  __shared__ float csb[64];
  __shared__ float rsb[64];
  int g = blockIdx.x;
  int t = threadIdx.x;          // 0..511
  int lane = t & 63;
  int wv   = t >> 6;            // 0..7
  int start = (g*N_NODES + 63) >> 6;
  int end   = ((g + 1)*N_NODES + 63) >> 6;
  int cnt = end - start;        // 156 or 157
  const float* hg = h + (size_t)start*64;
  for (int idx = t; idx < cnt*64; idx += 512)
    hc[(idx >> 6)*65 + (idx & 63)] = hg[idx];
  if (t < 64){ hsb[t] = 0.0f; csb[t] = 0.0f; rsb[t] = 0.0f; }
  __syncthreads();
  for (int step = 0; step < S2S_STEPS; ++step){
    float ev = -1e30f;
    if (t < cnt){
      float a = 0.0f;
      const float* hr = &hc[t*65];
      for (int i = 0; i < 64; ++i) a = fmaf(hr[i], hsb[i], a);
      ev = a;
    }
    float v = ev;
    for (int o = 32; o > 0; o >>= 1) v = fmaxf(v, __shfl_xor(v, o));
    if (lane == 0) wredA[wv] = v;
    __syncthreads();                                      // S1
    float mx = wredA[0];
    #pragma unroll
    for (int i = 1; i < 8; ++i) mx = fmaxf(mx, wredA[i]);
    float ex = (t < cnt) ? expf(ev - mx) : 0.0f;
    float sv = ex;
    for (int o = 32; o > 0; o >>= 1) sv += __shfl_xor(sv, o);
    if (lane == 0) wredB[wv] = sv;
    __syncthreads();                                      // S2
    float ssum = 0.0f;
    #pragma unroll
    for (int i = 0; i < 8; ++i) ssum += wredB[i];
    if (t < cnt) ea[t] = ex / (ssum + 1e-16f);
    __syncthreads();                                      // S3
    {
      int n0 = wv*20;
      int n1 = n0 + 20; if (n1 > cnt) n1 = cnt;
      float r = 0.0f;
      for (int n = n0; n < n1; ++n)
        r = fmaf(ea[n], hc[n*65 + lane], r);
      rsp[wv][lane] = r;
    }
    __syncthreads();                                      // S4
    if (t < 64){
      float r = rsp[0][t] + rsp[1][t] + rsp[2][t] + rsp[3][t]
              + rsp[4][t] + rsp[5][t] + rsp[6][t] + rsp[7][t];
      rsb[t] = r;
      x[t]        = hsb[t];
      x[64 + t]   = r;
      x[128 + t]  = hsb[t];
    }
    __syncthreads();                                      // S5
    {
      int gate = t & 255;
      int half = t >> 8;
      float gl = 0.0f;
      if (half == 0){
        const float* wr = Wli + (size_t)gate*128;
        for (int jj = 0; jj < 96; ++jj) gl = fmaf(x[jj], wr[jj], gl);
      } else {
        const float* wr = Wli + (size_t)gate*128;
        for (int jj = 96; jj < 128; ++jj) gl = fmaf(x[jj], wr[jj], gl);
        const float* wh = Wlh + (size_t)gate*64;
        for (int jj = 0; jj < 64; ++jj) gl = fmaf(x[128 + jj], wh[jj], gl);
      }
      gpart[t] = gl;
    }
    __syncthreads();                                      // S6
    if (t < 64){
      float iv = sigf (gpart[t]       + gpart[t + 256]       + bli[t]       + blh[t]);
      float fv = sigf (gpart[64 + t]  + gpart[64 + t + 256]  + bli[64 + t]  + blh[64 + t]);
      float gv = tanhf(gpart[128 + t] + gpart[128 + t + 256] + bli[128 + t] + blh[128 + t]);
      float ov = sigf (gpart[192 + t] + gpart[192 + t + 256] + bli[192 + t] + blh[192 + t]);
      float c  = fv*csb[t] + iv*gv;
      csb[t] = c;
      hsb[t] = ov*tanhf(c);
    }
    __syncthreads();                                      // S7
  }
  float rv = 0.0f;
  if (t < 64){
    float v = bm1[t];
    for (int j = 0; j < 64; ++j) v = fmaf(hsb[j], Wm1[(size_t)j*64 + t],        v);
    for (int j = 0; j < 64; ++j) v = fmaf(rsb[j], Wm1[(size_t)(64 + j)*64 + t], v);
    v = fmaxf(v, 0.0f);
    rv = v * Wm2[t];
  }
  for (int o = 32; o > 0; o >>= 1) rv += __shfl_xor(rv, o);
  if (lane == 0) wredA[wv] = rv;
  __syncthreads();
  if (t == 0) out[g] = wredA[0] + wredA[1] + wredA[2] + wredA[3]
                     + wredA[4] + wredA[5] + wredA[6] + wredA[7] + bm2[0];
}

extern "C" void kernel_launch(void* const* d_in, const int* in_sizes, int n_in,
                              void* d_out, int out_size, void* d_ws, size_t ws_size,
                              hipStream_t stream){
  (void)in_sizes; (void)n_in; (void)out_size;

  const float* nf  = (const float*)d_in[0];
  const float* ef  = (const float*)d_in[1];
  const int*   ei  = (const int*)d_in[2];
  const float* Wp  = (const float*)d_in[4];
  const float* bp  = (const float*)d_in[5];
  const float* We1 = (const float*)d_in[6];
  const float* be1 = (const float*)d_in[7];
  const float* We2 = (const float*)d_in[8];
  const float* be2 = (const float*)d_in[9];
  const float* Wg  = (const float*)d_in[10];
  const float* Wh  = (const float*)d_in[11];
  const float* bg  = (const float*)d_in[12];
  const float* bhb = (const float*)d_in[13];
  const float* Wli = (const float*)d_in[14];
  const float* Wlh = (const float*)d_in[15];
  const float* bli = (const float*)d_in[16];
  const float* blh = (const float*)d_in[17];
  const float* Wm1 = (const float*)d_in[18];
  const float* bm1 = (const float*)d_in[19];
  const float* Wm2 = (const float*)d_in[20];
  const float* bm2 = (const float*)d_in[21];

  float* out = (float*)d_out;
  float* ws  = (float*)d_ws;

  float* h    = ws;                         //   640000
  float* m    = ws + 640000;                //   640000
  float* bh   = ws + 1280000;               //   640000
  float* Mm   = ws + 1920000;               //   524288  (fallback)
  float* WgT  = ws + 2444288;               //    12288
  float* WhT  = ws + 2456576;               //    12288
  float* Hid  = ws + 2468864;               //  6400000 (fp32 fallback / fp16 main)
  half_t* Hid16 = (half_t*)Hid;
  int*   deg    = (int*)(ws + 8868864);     // src-CSR
  int*   rowptr = deg + 10000;
  int*   cursor = rowptr + 10001;
  int*   csr    = cursor + 10000;
  half_t* AT  = (half_t*)(ws + 8948880);    // unused in r14 (layout kept)
  half_t* BT  = (half_t*)(ws + 9268880);
  const size_t C_OFF = 9531024;             // floats
  half_t* C   = (half_t*)(ws + C_OFF);      // fallback chunked-C buffer
  (void)AT;

  long long c_halves = ((long long)ws_size - (long long)C_OFF*4) / 2;
  int NC = (c_halves > 0) ? (int)(c_halves / 8192) : 0;
  if (NC > N_NODES) NC = N_NODES;
  int use_c_path = (NC >= 512);
  int use_mfma   = (NC >= N_NODES);   // proven ws-size gate

  k_proj<<<(N_NODES*HID + 255)/256, 256, 0, stream>>>(nf, Wp, bp, h);

  if (use_c_path){
    k_twg <<<(192*64 + 255)/256, 256, 0, stream>>>(Wg, Wh, WgT, WhT);
    k_zero<<<(10000 + 255)/256, 256, 0, stream>>>((float*)deg, 10000);
    k_hist<<<(N_EDGES + 255)/256, 256, 0, stream>>>(ei + N_EDGES, deg);   // by src
    k_scan<<<1, 256, 0, stream>>>(deg, rowptr, cursor);
    k_scatter<<<(N_EDGES + 255)/256, 256, 0, stream>>>(ei + N_EDGES, cursor, csr);
    if (use_mfma){
      k_ehid16<<<(N_EDGES*EHID + 255)/256, 256, 0, stream>>>(ef, We1, be1, Hid16);
      k_w2bt<<<(512*2*64*8 + 255)/256, 256, 0, stream>>>(We2, BT);
      for (int step = 0; step < T_STEPS; ++step){
        k_prep<<<(N_NODES*HID + 255)/256, 256, 0, stream>>>(h, be2, m, bh);
        dim3 grid(625/TMB, 4, 2);
        MPNN_55705725829535_kernel<<<grid, 256, 0, stream>>>(
            h, BT, rowptr, csr, ei, Hid16, bh, m);
        k_gru<<<625, 256, 0, stream>>>(h, m, WgT, WhT, bg, bhb);
      }
    } else {
      k_ehid<<<(N_EDGES*EHID + 255)/256, 256, 0, stream>>>(ef, We1, be1, Hid);
      k_tw2<<<(64*8192)/256, 256, 0, stream>>>(We2, Mm);
      for (int step = 0; step < T_STEPS; ++step){
        k_zero<<<(N_NODES*HID + 255)/256, 256, 0, stream>>>(m, N_NODES*HID);
        k_bh<<<(N_NODES*HID + 255)/256, 256, 0, stream>>>(h, be2, bh);
        for (int lo = 0; lo < N_NODES; lo += NC){
          int hi = (lo + NC < N_NODES) ? lo + NC : N_NODES;
          int cnt = hi - lo;
          dim3 grid((cnt + 15)/16, 16);
          k_cgemm<<<grid, 256, 0, stream>>>(h, Mm, C, lo, hi);
          k_msg_csr<<<(cnt + 3)/4, 256, 0, stream>>>(
              rowptr, csr, ei, Hid, C, bh, m, lo, hi);
        }
        k_gru<<<625, 256, 0, stream>>>(h, m, WgT, WhT, bg, bhb);
      }
    }
  } else {
    k_twg <<<(192*64 + 255)/256, 256, 0, stream>>>(Wg, Wh, WgT, WhT);
    for (int step = 0; step < T_STEPS; ++step){
      k_zero<<<(N_NODES*HID + 255)/256, 256, 0, stream>>>(m, N_NODES*HID);
      k_msg_fb<<<N_EDGES, 64, 0, stream>>>(ei, ef, We1, be1, We2, be2, h, m);
      k_gru<<<625, 256, 0, stream>>>(h, m, WgT, WhT, bg, bhb);
    }
  }
  k_s2s<<<N_GRAPHS, 512, 0, stream>>>(h, Wli, Wlh, bli, blh,
                                      Wm1, bm1, Wm2, bm2, out);
}

// Round 15
// 543.965 us; speedup vs baseline: 1.0333x; 1.0333x over previous
//
#include <hip/hip_runtime.h>

#define N_NODES   10000
#define N_EDGES   50000
#define N_GRAPHS  64
#define NODE_DIM  32
#define EDGE_DIM  16
#define HID       64
#define EHID      128
#define T_STEPS   3
#define S2S_STEPS 6
#define TMB       5     // tm tiles per block (BT register-amortization)

typedef _Float16 half_t;
typedef _Float16 f16x8 __attribute__((ext_vector_type(8)));
typedef float    f32x4 __attribute__((ext_vector_type(4)));

__device__ __forceinline__ float sigf(float x){ return 1.0f/(1.0f + expf(-x)); }

__global__ void k_zero(float* p, int n){
  int i = blockIdx.x*256 + threadIdx.x;
  if (i < n) p[i] = 0.0f;
}

// h = nf @ W_proj + b_proj   (N x 64)
// [SESSION NOTES — measured, do not retry:
//  - r14 AT-elimination (A-frags direct from fp32 h): 62->67.5us, FETCH
//    38.9->43.9MB — fp32 reads double critical-path bytes; AT fp16 staging
//    is measured-optimal.
//  - merged prep-style kernels (r10 k_gru_prep, r11 k_proj_prep): ~75-97us
//    near-idle stall windows; separate kernels measured-fast.
//  - r10 register Hid16-gather prefetch in fused kernel: 62->93us.
//  - r12 LDS double-buffered edge prefetch: 62->65us (neutral-negative).
//  - r7/r8 atomic-free Msg detour: net worse than atomics (606/622 vs 581).
//  - r1 coalesced-WcT s2s gates: 56->95us.]
__global__ void k_proj(const float* __restrict__ nf, const float* __restrict__ Wp,
                       const float* __restrict__ bp, float* __restrict__ h){
  int idx = blockIdx.x*256 + threadIdx.x;
  if (idx >= N_NODES*HID) return;
  int n = idx >> 6;
  int c = idx & 63;
  float acc = bp[c];
  const float* row = nf + (size_t)n*NODE_DIM;
  for (int j = 0; j < NODE_DIM; ++j)
    acc = fmaf(row[j], Wp[j*HID + c], acc);
  h[idx] = acc;
}

// Mm (fp32, fallback path)
__global__ void k_tw2(const float* __restrict__ W2, float* __restrict__ Mm){
  int idx = blockIdx.x*256 + threadIdx.x;
  if (idx >= 64*8192) return;
  int j = idx >> 13; int o = idx & 8191; int k = o >> 6; int i = o & 63;
  Mm[idx] = W2[(size_t)k*4096 + i*64 + j];
}

// BT: W2 in MFMA B-fragment order (fp16), built once.
__global__ void k_w2bt(const float* __restrict__ W2, half_t* __restrict__ BT){
  int idx = blockIdx.x*256 + threadIdx.x;
  if (idx >= 512*2*64*8) return;
  int j    = idx & 7;
  int lane = (idx >> 3) & 63;
  int tk   = (idx >> 9) & 1;
  int tn   = idx >> 10;
  int k = tk*32 + ((lane >> 4) << 3) + j;
  int o = tn*16 + (lane & 15);
  BT[idx] = (half_t)W2[(size_t)(o >> 6)*4096 + (o & 63)*64 + k];
}

// Fused per-step prep: m=0, bh = be2-rowdot(h), AT = h in A-fragment order.
__global__ void k_prep(const float* __restrict__ h, const float* __restrict__ be2,
                       float* __restrict__ m, float* __restrict__ bhp,
                       half_t* __restrict__ AT){
  int idx = blockIdx.x*256 + threadIdx.x;
  if (idx >= N_NODES*HID) return;
  m[idx] = 0.0f;
  int n = idx >> 6, i = idx & 63;
  float acc = 0.0f;
  const float* row = be2 + (size_t)i*64;
  const float* hr  = h + (size_t)n*64;
  for (int j = 0; j < 64; ++j)
    acc = fmaf(row[j], hr[j], acc);
  bhp[idx] = acc;
  int j    = idx & 7;
  int lane = (idx >> 3) & 63;
  int tk   = (idx >> 9) & 1;
  int tm   = idx >> 10;
  int mrow = tm*16 + (lane & 15);
  int k    = tk*32 + ((lane >> 4) << 3) + j;
  AT[idx] = (half_t)h[(size_t)mrow*64 + k];
}

// GRU weight transposes
__global__ void k_twg(const float* __restrict__ Wg, const float* __restrict__ Wh,
                      float* __restrict__ WgT, float* __restrict__ WhT){
  int idx = blockIdx.x*256 + threadIdx.x;
  if (idx >= 192*64) return;
  int row = idx >> 6;
  int j   = idx & 63;
  WgT[j*192 + row] = Wg[(size_t)row*64 + j];
  WhT[j*192 + row] = Wh[(size_t)row*64 + j];
}

// Hid = relu(ef @ W_e1 + b_e1)  fp32 (fallback path)
__global__ void k_ehid(const float* __restrict__ ef, const float* __restrict__ W1,
                       const float* __restrict__ b1, float* __restrict__ Hid){
  int idx = blockIdx.x*256 + threadIdx.x;
  if (idx >= N_EDGES*EHID) return;
  int e = idx >> 7, c = idx & 127;
  float acc = b1[c];
  const float* er = ef + (size_t)e*EDGE_DIM;
  for (int j = 0; j < EDGE_DIM; ++j)
    acc = fmaf(er[j], W1[j*EHID + c], acc);
  Hid[idx] = fmaxf(acc, 0.0f);
}

// Hid16 = relu(ef @ W_e1 + b_e1) in fp16 (MFMA message path)
__global__ void k_ehid16(const float* __restrict__ ef, const float* __restrict__ W1,
                         const float* __restrict__ b1, half_t* __restrict__ Hid16){
  int idx = blockIdx.x*256 + threadIdx.x;
  if (idx >= N_EDGES*EHID) return;
  int e = idx >> 7, c = idx & 127;
  float acc = b1[c];
  const float* er = ef + (size_t)e*EDGE_DIM;
  for (int j = 0; j < EDGE_DIM; ++j)
    acc = fmaf(er[j], W1[j*EHID + c], acc);
  Hid16[idx] = (half_t)fmaxf(acc, 0.0f);
}

// bh[n,i] = sum_j be2[i*64+j] * h[n,j]  (fallback path)
__global__ void k_bh(const float* __restrict__ h, const float* __restrict__ be2,
                     float* __restrict__ bh){
  int idx = blockIdx.x*256 + threadIdx.x;
  if (idx >= N_NODES*HID) return;
  int n = idx >> 6, i = idx & 63;
  float acc = 0.0f;
  const float* row = be2 + (size_t)i*64;
  const float* hr  = h + (size_t)n*64;
  for (int j = 0; j < 64; ++j)
    acc = fmaf(row[j], hr[j], acc);
  bh[idx] = acc;
}

// ---- CSR builders ----
__global__ void k_hist(const int* __restrict__ ids, int* __restrict__ deg){
  int e = blockIdx.x*256 + threadIdx.x;
  if (e >= N_EDGES) return;
  atomicAdd(&deg[ids[e]], 1);
}

__global__ void k_scan(const int* __restrict__ deg, int* __restrict__ rowptr,
                       int* __restrict__ cursor){
  __shared__ int part[256];
  int t = threadIdx.x;
  int base = t*40;
  int s = 0;
  for (int i = 0; i < 40; ++i){
    int idx = base + i;
    if (idx < N_NODES) s += deg[idx];
  }
  part[t] = s;
  __syncthreads();
  for (int off = 1; off < 256; off <<= 1){
    int v = (t >= off) ? part[t - off] : 0;
    __syncthreads();
    part[t] += v;
    __syncthreads();
  }
  int run = (t > 0) ? part[t - 1] : 0;
  for (int i = 0; i < 40; ++i){
    int idx = base + i;
    if (idx < N_NODES){
      rowptr[idx] = run;
      cursor[idx] = run;
      run += deg[idx];
    }
  }
  if (t == 255) rowptr[N_NODES] = run;
}

__global__ void k_scatter(const int* __restrict__ ids, int* __restrict__ cursor,
                          int* __restrict__ csr){
  int e = blockIdx.x*256 + threadIdx.x;
  if (e >= N_EDGES) return;
  int v = ids[e];
  int pos = atomicAdd(&cursor[v], 1);
  csr[pos] = e;
}

// ---- FUSED cgemm + message kernel (mfma path) — EXACT r9/r13 version ----
// (measured session-best twice: 547.9us / 547.4us total, 62.4us/dispatch)
// BT register-resident across TMB=5 tiles (cuts BT L2 traffic 5x — the one
// fused-kernel change that measured positive); fp16 AT staging (r14 direct-h
// read regressed); cooperative edge/dst prefetch; atomic scatter.
__global__ __launch_bounds__(256, 2)
void MPNN_55705725829535_kernel(const half_t* __restrict__ AT,
                                const half_t* __restrict__ BT,
                                const int* __restrict__ rowptr,
                                const int* __restrict__ csr,
                                const int* __restrict__ ei,
                                const half_t* __restrict__ Hid16,
                                const float* __restrict__ bh,
                                float* __restrict__ m){
  __shared__ half_t Ct[16][2][520];
  __shared__ int edgW[4][4][16];
  __shared__ int dstW[4][4][16];
  int wv   = threadIdx.x >> 6;
  int lane = threadIdx.x & 63;
  int quad = lane >> 4;
  int colb = lane & 15;
  int tmg = blockIdx.x;          // 0..124 (group of TMB tm tiles)
  int q   = blockIdx.y;          // 0..3   (i-quarter)
  int kh  = blockIdx.z;          // 0..1   (k-half)

  // ---- load this block's BT slice into registers (once) ----
  f16x8 B0r[2][8], B1r[2][8];
  #pragma unroll
  for (int ktl = 0; ktl < 2; ++ktl)
    #pragma unroll
    for (int jj = 0; jj < 8; ++jj){
      int ke = (kh*2 + ktl)*32 + wv*8 + jj;
      const f16x8* Bb = (const f16x8*)BT + (size_t)(ke*4 + q)*128;
      B0r[ktl][jj] = Bb[lane];
      B1r[ktl][jj] = Bb[64 + lane];
    }

  for (int tt = 0; tt < TMB; ++tt){
    int tm = tmg*TMB + tt;
    const f16x8* Ab = (const f16x8*)AT + (size_t)tm*128;
    f16x8 a0 = Ab[lane];
    f16x8 a1 = Ab[64 + lane];

    // ---- cooperative prefetch of edge ids + dst ids for this wave's 4 nodes
    {
      int nodeL = wv*4 + quad;          // lane-quad -> node c
      int sL = tm*16 + nodeL;
      int begL = rowptr[sL];
      int endL = rowptr[sL + 1];
      int eL = (colb < endL - begL) ? csr[begL + colb] : -1;
      edgW[wv][quad][colb] = eL;
      dstW[wv][quad][colb] = (eL >= 0) ? ei[eL] : -1;
    }

    // ---- phase 1: C-slice GEMM into LDS (register B-frags, 32 MFMA) ----
    #pragma unroll
    for (int ktl = 0; ktl < 2; ++ktl){
      f32x4 acc[8];
      #pragma unroll
      for (int jj = 0; jj < 8; ++jj){
        acc[jj][0]=0.f; acc[jj][1]=0.f; acc[jj][2]=0.f; acc[jj][3]=0.f;
      }
      #pragma unroll
      for (int jj = 0; jj < 8; ++jj){
        acc[jj] = __builtin_amdgcn_mfma_f32_16x16x32_f16(a0, B0r[ktl][jj], acc[jj], 0, 0, 0);
        acc[jj] = __builtin_amdgcn_mfma_f32_16x16x32_f16(a1, B1r[ktl][jj], acc[jj], 0, 0, 0);
      }
      #pragma unroll
      for (int r = 0; r < 4; ++r){
        int node = quad*4 + r;       // 0..15
        f16x8 v;
        #pragma unroll
        for (int jj = 0; jj < 8; ++jj) v[jj] = (half_t)acc[jj][r];
        *(f16x8*)&Ct[node][ktl][(wv*16 + colb)*8] = v;
      }
    }
    __syncthreads();

    // ---- phase 2: per-node message MFMAs (k-half), atomic scatter ----
    for (int c = 0; c < 4; ++c){
      int node = wv*4 + c;           // 0..15
      int s = tm*16 + node;
      int beg  = rowptr[s];
      int endp = rowptr[s + 1];
      if (beg == endp) continue;
      f16x8 B0 = *(const f16x8*)&Ct[node][0][lane*8];
      f16x8 B1 = *(const f16x8*)&Ct[node][1][lane*8];
      float bhc = (kh == 0) ? bh[(size_t)s*64 + q*16 + colb] : 0.0f;
      // group 0: prefetched edge/dst lists
      int gn0 = endp - beg; if (gn0 > 16) gn0 = 16;
      {
        f16x8 A0, A1;
        int e = (colb < gn0) ? edgW[wv][c][colb] : -1;
        if (e >= 0){
          const f16x8* Hb = (const f16x8*)(Hid16 + (size_t)e*128) + quad;
          A0 = Hb[(kh*2 + 0)*4];
          A1 = Hb[(kh*2 + 1)*4];
        } else {
          #pragma unroll
          for (int p = 0; p < 8; ++p){ A0[p] = (half_t)0; A1[p] = (half_t)0; }
        }
        f32x4 acc;
        acc[0]=0.f; acc[1]=0.f; acc[2]=0.f; acc[3]=0.f;
        acc = __builtin_amdgcn_mfma_f32_16x16x32_f16(A0, B0, acc, 0, 0, 0);
        acc = __builtin_amdgcn_mfma_f32_16x16x32_f16(A1, B1, acc, 0, 0, 0);
        #pragma unroll
        for (int r = 0; r < 4; ++r){
          int jrow = quad*4 + r;
          if (jrow < gn0){
            int d = dstW[wv][c][jrow];
            atomicAdd(&m[(size_t)d*64 + q*16 + colb], acc[r] + bhc);
          }
        }
      }
      // remaining groups (deg > 16; rare)
      for (int gbeg = beg + 16; gbeg < endp; gbeg += 16){
        int gn = endp - gbeg; if (gn > 16) gn = 16;
        if (lane < 16){
          int e2 = (lane < gn) ? csr[gbeg + lane] : -1;
          edgW[wv][c][lane] = e2;
          dstW[wv][c][lane] = (e2 >= 0) ? ei[e2] : -1;
        }
        f16x8 A0, A1;
        int e = (colb < gn) ? edgW[wv][c][colb] : -1;
        if (e >= 0){
          const f16x8* Hb = (const f16x8*)(Hid16 + (size_t)e*128) + quad;
          A0 = Hb[(kh*2 + 0)*4];
          A1 = Hb[(kh*2 + 1)*4];
        } else {
          #pragma unroll
          for (int p = 0; p < 8; ++p){ A0[p] = (half_t)0; A1[p] = (half_t)0; }
        }
        f32x4 acc;
        acc[0]=0.f; acc[1]=0.f; acc[2]=0.f; acc[3]=0.f;
        acc = __builtin_amdgcn_mfma_f32_16x16x32_f16(A0, B0, acc, 0, 0, 0);
        acc = __builtin_amdgcn_mfma_f32_16x16x32_f16(A1, B1, acc, 0, 0, 0);
        #pragma unroll
        for (int r = 0; r < 4; ++r){
          int jrow = quad*4 + r;
          if (jrow < gn){
            int d = dstW[wv][c][jrow];
            atomicAdd(&m[(size_t)d*64 + q*16 + colb], acc[r] + bhc);
          }
        }
      }
    }
    __syncthreads();
  }
}

// scalar cgemm (fallback, chunked)
__global__ void k_cgemm(const float* __restrict__ h, const float* __restrict__ Mm,
                        half_t* __restrict__ C, int lo, int hi){
  __shared__ float hs[16][64];
  int n0 = lo + blockIdx.x*16;
  int o0 = blockIdx.y*256 + threadIdx.x;
  for (int idx = threadIdx.x; idx < 16*64; idx += 256){
    int nn = idx >> 6, j = idx & 63;
    int node = n0 + nn;
    hs[nn][j] = (node < hi) ? h[(size_t)node*64 + j] : 0.0f;
  }
  __syncthreads();
  float acc0[16], acc1[16];
  #pragma unroll
  for (int nn = 0; nn < 16; ++nn){ acc0[nn] = 0.0f; acc1[nn] = 0.0f; }
  for (int j4 = 0; j4 < 16; ++j4){
    const float* M0 = Mm + (size_t)(j4*4)*8192;
    float a0 = M0[o0],            b0 = M0[o0 + 4096];
    float a1 = M0[8192 + o0],     b1 = M0[8192 + o0 + 4096];
    float a2 = M0[2*8192 + o0],   b2 = M0[2*8192 + o0 + 4096];
    float a3 = M0[3*8192 + o0],   b3 = M0[3*8192 + o0 + 4096];
    #pragma unroll
    for (int nn = 0; nn < 16; ++nn){
      float4 hv = *(const float4*)&hs[nn][j4*4];
      acc0[nn] = fmaf(hv.x, a0, acc0[nn]);
      acc1[nn] = fmaf(hv.x, b0, acc1[nn]);
      acc0[nn] = fmaf(hv.y, a1, acc0[nn]);
      acc1[nn] = fmaf(hv.y, b1, acc1[nn]);
      acc0[nn] = fmaf(hv.z, a2, acc0[nn]);
      acc1[nn] = fmaf(hv.z, b2, acc1[nn]);
      acc0[nn] = fmaf(hv.w, a3, acc0[nn]);
      acc1[nn] = fmaf(hv.w, b3, acc1[nn]);
    }
  }
  #pragma unroll
  for (int nn = 0; nn < 16; ++nn){
    int node = n0 + nn;
    if (node < hi){
      half_t* Cr = C + (size_t)(node - lo)*8192;
      Cr[o0]        = (half_t)acc0[nn];
      Cr[o0 + 4096] = (half_t)acc1[nn];
    }
  }
}

// old-style streaming msg kernel (fallback path)
__global__ void k_msg_csr(const int* __restrict__ rowptr,
                          const int* __restrict__ csr,
                          const int* __restrict__ ei,
                          const float* __restrict__ Hid,
                          const half_t* __restrict__ C,
                          const float* __restrict__ bh,
                          float* __restrict__ m, int lo, int hi){
  __shared__ float hidL[4][8][128];
  int wave = threadIdx.x >> 6;
  int lane = threadIdx.x & 63;
  int s = lo + blockIdx.x*4 + wave;
  if (s >= hi) return;
  int beg = rowptr[s];
  int endp = rowptr[s + 1];
  if (beg == endp) return;
  float bhv = bh[(size_t)s*64 + lane];
  const half_t* Cb = C + (size_t)(s - lo)*8192 + lane;
  float (*hl)[128] = hidL[wave];
  for (int gbeg = beg; gbeg < endp; gbeg += 8){
    int gn = endp - gbeg; if (gn > 8) gn = 8;
    int dsts[8];
    int e0 = csr[gbeg];
    #pragma unroll
    for (int j = 0; j < 8; ++j){
      int e = (j < gn) ? csr[gbeg + j] : e0;
      dsts[j] = ei[e];
      hl[j][lane]      = Hid[(size_t)e*128 + lane];
      hl[j][lane + 64] = Hid[(size_t)e*128 + 64 + lane];
    }
    float acc[8];
    #pragma unroll
    for (int j = 0; j < 8; ++j) acc[j] = 0.0f;
    #pragma unroll 4
    for (int k = 0; k < 128; ++k){
      float c = (float)Cb[k*64];
      #pragma unroll
      for (int j = 0; j < 8; ++j)
        acc[j] = fmaf(hl[j][k], c, acc[j]);
    }
    for (int j = 0; j < gn; ++j)
      atomicAdd(&m[(size_t)dsts[j]*64 + lane], acc[j] + bhv);
  }
}

// fallback per-edge bilinear
__global__ void k_msg_fb(const int* __restrict__ ei, const float* __restrict__ ef,
                         const float* __restrict__ W1, const float* __restrict__ b1,
                         const float* __restrict__ W2, const float* __restrict__ be2,
                         const float* __restrict__ h, float* __restrict__ m){
  __shared__ float HidL[EHID];
  __shared__ __align__(16) float hsL[HID];
  int e = blockIdx.x;
  int t = threadIdx.x;
  int src = ei[N_EDGES + e];
  int dst = ei[e];
  {
    float a0 = b1[t];
    float a1 = b1[t + 64];
    const float* er = ef + (size_t)e*EDGE_DIM;
    for (int j = 0; j < EDGE_DIM; ++j){
      float ev = er[j];
      a0 = fmaf(ev, W1[j*EHID + t],      a0);
      a1 = fmaf(ev, W1[j*EHID + t + 64], a1);
    }
    HidL[t]      = fmaxf(a0, 0.0f);
    HidL[t + 64] = fmaxf(a1, 0.0f);
    hsL[t] = h[(size_t)src*64 + t];
  }
  __syncthreads();
  float acc = 0.0f;
  for (int k = 0; k < EHID; ++k){
    float s = HidL[k];
    if (s != 0.0f){
      const float* w = W2 + (size_t)k*4096 + t*64;
      float partial = 0.0f;
      for (int j = 0; j < 64; ++j)
        partial = fmaf(hsL[j], w[j], partial);
      acc = fmaf(s, partial, acc);
    }
  }
  {
    const float* w = be2 + (size_t)t*64;
    for (int j = 0; j < 64; ++j)
      acc = fmaf(hsL[j], w[j], acc);
  }
  atomicAdd(&m[(size_t)dst*64 + t], acc);
}

// GRU: 256 threads = 4 waves, 16 nodes/block (4 per wave).
__global__ void k_gru(float* __restrict__ h, const float* __restrict__ m,
                      const float* __restrict__ WgT, const float* __restrict__ WhT,
                      const float* __restrict__ bg, const float* __restrict__ bhb){
  __shared__ float mld[16][64];
  __shared__ float hld[16][64];
  int t  = threadIdx.x;
  int i  = t & 63;
  int wv = t >> 6;                  // 0..3
  int n0 = blockIdx.x*16;           // 625*16 == 10000 exactly
  for (int idx = t; idx < 16*64; idx += 256){
    int nn = idx >> 6, j = idx & 63;
    int node = n0 + nn;
    mld[nn][j] = m[(size_t)node*64 + j];
    hld[nn][j] = h[(size_t)node*64 + j];
  }
  __syncthreads();
  float xr[4], xz[4], xn[4], hr[4], hz[4], hn[4];
  #pragma unroll
  for (int c = 0; c < 4; ++c){
    xr[c] = bg[i];  xz[c] = bg[64 + i];  xn[c] = bg[128 + i];
    hr[c] = bhb[i]; hz[c] = bhb[64 + i]; hn[c] = bhb[128 + i];
  }
  for (int j = 0; j < 64; ++j){
    const float* wg = WgT + j*192;
    const float* wh = WhT + j*192;
    float wgr = wg[i], wgz = wg[64 + i], wgn = wg[128 + i];
    float whr = wh[i], whz = wh[64 + i], whn = wh[128 + i];
    #pragma unroll
    for (int c = 0; c < 4; ++c){
      int nn = wv*4 + c;
      float mj = mld[nn][j];
      float hj = hld[nn][j];
      xr[c] = fmaf(mj, wgr, xr[c]);
      xz[c] = fmaf(mj, wgz, xz[c]);
      xn[c] = fmaf(mj, wgn, xn[c]);
      hr[c] = fmaf(hj, whr, hr[c]);
      hz[c] = fmaf(hj, whz, hz[c]);
      hn[c] = fmaf(hj, whn, hn[c]);
    }
  }
  #pragma unroll
  for (int c = 0; c < 4; ++c){
    int nn = wv*4 + c;
    float r  = sigf(xr[c] + hr[c]);
    float z  = sigf(xz[c] + hz[c]);
    float nv = tanhf(xn[c] + r*hn[c]);
    h[(size_t)(n0 + nn)*64 + i] = (1.0f - z)*nv + z*hld[nn][i];
  }
}

// Set2Set + LSTM + readout; 512 threads (proven kernel — do not touch).
__global__ void k_s2s(const float* __restrict__ h,
                      const float* __restrict__ Wli, const float* __restrict__ Wlh,
                      const float* __restrict__ bli, const float* __restrict__ blh,
                      const float* __restrict__ Wm1, const float* __restrict__ bm1,
                      const float* __restrict__ Wm2, const float* __restrict__ bm2,
                      float* __restrict__ out){
  __shared__ float hc[157*65];
  __shared__ float ea[160];
  __shared__ float x[192];
  __shared__ float gpart[512];
  __shared__ float rsp[8][64];
  __shared__ float wredA[8];
  __shared__ float wredB[8];
  __shared__ float hsb[64];
  __shared__ float csb[64];
  __shared__ float rsb[64];
  int g = blockIdx.x;
  int t = threadIdx.x;          // 0..511
  int lane = t & 63;
  int wv   = t >> 6;            // 0..7
  int start = (g*N_NODES + 63) >> 6;
  int end   = ((g + 1)*N_NODES + 63) >> 6;
  int cnt = end - start;        // 156 or 157
  const float* hg = h + (size_t)start*64;
  for (int idx = t; idx < cnt*64; idx += 512)
    hc[(idx >> 6)*65 + (idx & 63)] = hg[idx];
  if (t < 64){ hsb[t] = 0.0f; csb[t] = 0.0f; rsb[t] = 0.0f; }
  __syncthreads();
  for (int step = 0; step < S2S_STEPS; ++step){
    float ev = -1e30f;
    if (t < cnt){
      float a = 0.0f;
      const float* hr = &hc[t*65];
      for (int i = 0; i < 64; ++i) a = fmaf(hr[i], hsb[i], a);
      ev = a;
    }
    float v = ev;
    for (int o = 32; o > 0; o >>= 1) v = fmaxf(v, __shfl_xor(v, o));
    if (lane == 0) wredA[wv] = v;
    __syncthreads();                                      // S1
    float mx = wredA[0];
    #pragma unroll
    for (int i = 1; i < 8; ++i) mx = fmaxf(mx, wredA[i]);
    float ex = (t < cnt) ? expf(ev - mx) : 0.0f;
    float sv = ex;
    for (int o = 32; o > 0; o >>= 1) sv += __shfl_xor(sv, o);
    if (lane == 0) wredB[wv] = sv;
    __syncthreads();                                      // S2
    float ssum = 0.0f;
    #pragma unroll
    for (int i = 0; i < 8; ++i) ssum += wredB[i];
    if (t < cnt) ea[t] = ex / (ssum + 1e-16f);
    __syncthreads();                                      // S3
    {
      int n0 = wv*20;
      int n1 = n0 + 20; if (n1 > cnt) n1 = cnt;
      float r = 0.0f;
      for (int n = n0; n < n1; ++n)
        r = fmaf(ea[n], hc[n*65 + lane], r);
      rsp[wv][lane] = r;
    }
    __syncthreads();                                      // S4
    if (t < 64){
      float r = rsp[0][t] + rsp[1][t] + rsp[2][t] + rsp[3][t]
              + rsp[4][t] + rsp[5][t] + rsp[6][t] + rsp[7][t];
      rsb[t] = r;
      x[t]        = hsb[t];
      x[64 + t]   = r;
      x[128 + t]  = hsb[t];
    }
    __syncthreads();                                      // S5
    {
      int gate = t & 255;
      int half = t >> 8;
      float gl = 0.0f;
      if (half == 0){
        const float* wr = Wli + (size_t)gate*128;
        for (int jj = 0; jj < 96; ++jj) gl = fmaf(x[jj], wr[jj], gl);
      } else {
        const float* wr = Wli + (size_t)gate*128;
        for (int jj = 96; jj < 128; ++jj) gl = fmaf(x[jj], wr[jj], gl);
        const float* wh = Wlh + (size_t)gate*64;
        for (int jj = 0; jj < 64; ++jj) gl = fmaf(x[128 + jj], wh[jj], gl);
      }
      gpart[t] = gl;
    }
    __syncthreads();                                      // S6
    if (t < 64){
      float iv = sigf (gpart[t]       + gpart[t + 256]       + bli[t]       + blh[t]);
      float fv = sigf (gpart[64 + t]  + gpart[64 + t + 256]  + bli[64 + t]  + blh[64 + t]);
      float gv = tanhf(gpart[128 + t] + gpart[128 + t + 256] + bli[128 + t] + blh[128 + t]);
      float ov = sigf (gpart[192 + t] + gpart[192 + t + 256] + bli[192 + t] + blh[192 + t]);
      float c  = fv*csb[t] + iv*gv;
      csb[t] = c;
      hsb[t] = ov*tanhf(c);
    }
    __syncthreads();                                      // S7
  }
  float rv = 0.0f;
  if (t < 64){
    float v = bm1[t];
    for (int j = 0; j < 64; ++j) v = fmaf(hsb[j], Wm1[(size_t)j*64 + t],        v);
    for (int j = 0; j < 64; ++j) v = fmaf(rsb[j], Wm1[(size_t)(64 + j)*64 + t], v);
    v = fmaxf(v, 0.0f);
    rv = v * Wm2[t];
  }
  for (int o = 32; o > 0; o >>= 1) rv += __shfl_xor(rv, o);
  if (lane == 0) wredA[wv] = rv;
  __syncthreads();
  if (t == 0) out[g] = wredA[0] + wredA[1] + wredA[2] + wredA[3]
                     + wredA[4] + wredA[5] + wredA[6] + wredA[7] + bm2[0];
}

extern "C" void kernel_launch(void* const* d_in, const int* in_sizes, int n_in,
                              void* d_out, int out_size, void* d_ws, size_t ws_size,
                              hipStream_t stream){
  (void)in_sizes; (void)n_in; (void)out_size;

  const float* nf  = (const float*)d_in[0];
  const float* ef  = (const float*)d_in[1];
  const int*   ei  = (const int*)d_in[2];
  const float* Wp  = (const float*)d_in[4];
  const float* bp  = (const float*)d_in[5];
  const float* We1 = (const float*)d_in[6];
  const float* be1 = (const float*)d_in[7];
  const float* We2 = (const float*)d_in[8];
  const float* be2 = (const float*)d_in[9];
  const float* Wg  = (const float*)d_in[10];
  const float* Wh  = (const float*)d_in[11];
  const float* bg  = (const float*)d_in[12];
  const float* bhb = (const float*)d_in[13];
  const float* Wli = (const float*)d_in[14];
  const float* Wlh = (const float*)d_in[15];
  const float* bli = (const float*)d_in[16];
  const float* blh = (const float*)d_in[17];
  const float* Wm1 = (const float*)d_in[18];
  const float* bm1 = (const float*)d_in[19];
  const float* Wm2 = (const float*)d_in[20];
  const float* bm2 = (const float*)d_in[21];

  float* out = (float*)d_out;
  float* ws  = (float*)d_ws;

  float* h    = ws;                         //   640000
  float* m    = ws + 640000;                //   640000
  float* bh   = ws + 1280000;               //   640000
  float* Mm   = ws + 1920000;               //   524288  (fallback)
  float* WgT  = ws + 2444288;               //    12288
  float* WhT  = ws + 2456576;               //    12288
  float* Hid  = ws + 2468864;               //  6400000 (fp32 fallback / fp16 main)
  half_t* Hid16 = (half_t*)Hid;
  int*   deg    = (int*)(ws + 8868864);     // src-CSR
  int*   rowptr = deg + 10000;
  int*   cursor = rowptr + 10001;
  int*   csr    = cursor + 10000;
  half_t* AT  = (half_t*)(ws + 8948880);
  half_t* BT  = (half_t*)(ws + 9268880);
  const size_t C_OFF = 9531024;             // floats
  half_t* C   = (half_t*)(ws + C_OFF);      // fallback chunked-C buffer

  long long c_halves = ((long long)ws_size - (long long)C_OFF*4) / 2;
  int NC = (c_halves > 0) ? (int)(c_halves / 8192) : 0;
  if (NC > N_NODES) NC = N_NODES;
  int use_c_path = (NC >= 512);
  int use_mfma   = (NC >= N_NODES);   // proven ws-size gate

  k_proj<<<(N_NODES*HID + 255)/256, 256, 0, stream>>>(nf, Wp, bp, h);

  if (use_c_path){
    k_twg <<<(192*64 + 255)/256, 256, 0, stream>>>(Wg, Wh, WgT, WhT);
    k_zero<<<(10000 + 255)/256, 256, 0, stream>>>((float*)deg, 10000);
    k_hist<<<(N_EDGES + 255)/256, 256, 0, stream>>>(ei + N_EDGES, deg);   // by src
    k_scan<<<1, 256, 0, stream>>>(deg, rowptr, cursor);
    k_scatter<<<(N_EDGES + 255)/256, 256, 0, stream>>>(ei + N_EDGES, cursor, csr);
    if (use_mfma){
      k_ehid16<<<(N_EDGES*EHID + 255)/256, 256, 0, stream>>>(ef, We1, be1, Hid16);
      k_w2bt<<<(512*2*64*8 + 255)/256, 256, 0, stream>>>(We2, BT);
      for (int step = 0; step < T_STEPS; ++step){
        k_prep<<<(N_NODES*HID + 255)/256, 256, 0, stream>>>(h, be2, m, bh, AT);
        dim3 grid(625/TMB, 4, 2);
        MPNN_55705725829535_kernel<<<grid, 256, 0, stream>>>(
            AT, BT, rowptr, csr, ei, Hid16, bh, m);
        k_gru<<<625, 256, 0, stream>>>(h, m, WgT, WhT, bg, bhb);
      }
    } else {
      k_ehid<<<(N_EDGES*EHID + 255)/256, 256, 0, stream>>>(ef, We1, be1, Hid);
      k_tw2<<<(64*8192)/256, 256, 0, stream>>>(We2, Mm);
      for (int step = 0; step < T_STEPS; ++step){
        k_zero<<<(N_NODES*HID + 255)/256, 256, 0, stream>>>(m, N_NODES*HID);
        k_bh<<<(N_NODES*HID + 255)/256, 256, 0, stream>>>(h, be2, bh);
        for (int lo = 0; lo < N_NODES; lo += NC){
          int hi = (lo + NC < N_NODES) ? lo + NC : N_NODES;
          int cnt = hi - lo;
          dim3 grid((cnt + 15)/16, 16);
          k_cgemm<<<grid, 256, 0, stream>>>(h, Mm, C, lo, hi);
          k_msg_csr<<<(cnt + 3)/4, 256, 0, stream>>>(
              rowptr, csr, ei, Hid, C, bh, m, lo, hi);
        }
        k_gru<<<625, 256, 0, stream>>>(h, m, WgT, WhT, bg, bhb);
      }
    }
  } else {
    k_twg <<<(192*64 + 255)/256, 256, 0, stream>>>(Wg, Wh, WgT, WhT);
    for (int step = 0; step < T_STEPS; ++step){
      k_zero<<<(N_NODES*HID + 255)/256, 256, 0, stream>>>(m, N_NODES*HID);
      k_msg_fb<<<N_EDGES, 64, 0, stream>>>(ei, ef, We1, be1, We2, be2, h, m);
      k_gru<<<625, 256, 0, stream>>>(h, m, WgT, WhT, bg, bhb);
    }
  }
  k_s2s<<<N_GRAPHS, 512, 0, stream>>>(h, Wli, Wlh, bli, blh,
                                      Wm1, bm1, Wm2, bm2, out);
}